// Round 8
// baseline (62.358 us; speedup 1.0000x reference)
//
#include <hip/hip_runtime.h>
#include <hip/hip_bf16.h>
#include <hip/hip_fp16.h>
#include <math.h>

#define HH 4
#define BB 4
#define CC 32
#define VV 1000
#define LL 12
#define EE 20000
#define NBL (BB * LL)   /* 48 */
#define SS (HH * NBL)   /* 192 */
#define RCAP 128        /* padded CSR row capacity (max deg ~45 for this input) */
#define LALPHA 0.2f
#define NEG_CAP_F -9000000000000000.0f

typedef unsigned int uint;
typedef unsigned short ushort;

// ---------------------------------------------------------------------------
// k_h: h_g[slab][v][c] (f16), slab=h*NBL+b*LL+l; h = x·W.
// Block = 2 v x 4 h x 32 c (grid 500 x BB = 2000 blocks, ~8 waves/SIMD).
// vp is wave-uniform -> x row read via readfirstlane-uniform base (SMEM path,
// off the LDS pipe). x_s (3 KB LDS) serves only the s_src/s_dst dots.
// Blocks (y==0, x<4) zero cnt[].
// ---------------------------------------------------------------------------
__global__ __launch_bounds__(256) void k_h(const float* __restrict__ x,
                                           const float* __restrict__ W,
                                           const float* __restrict__ a,
                                           ushort* __restrict__ h_g,
                                           float* __restrict__ s_src,
                                           float* __restrict__ s_dst,
                                           int* __restrict__ cnt) {
  if (blockIdx.y == 0 && blockIdx.x < 4) {
    cnt[blockIdx.x * 256 + threadIdx.x] = 0;
  }

  __shared__ float W_lds[HH * CC * CC];   // 16 KB
  __shared__ float a_lds[HH * 2 * CC];    // 1 KB
  __shared__ float x_s[CC * 2 * LL];      // 3 KB (s-part only)
  __shared__ float wa[HH][2][CC];         // 512 B
  const int tid = threadIdx.x;
  const int b = blockIdx.y;
  const int v0 = blockIdx.x * 2;

  {
    const float4* Wf = (const float4*)W;
    float4* Wl = (float4*)W_lds;
    for (int i = tid; i < HH * CC * CC / 4; i += 256) Wl[i] = Wf[i];
  }
  a_lds[tid] = a[tid];   // HH*2*CC == 256
#pragma unroll
  for (int k = 0; k < 3; ++k) {
    int i = k * 256 + tid;
    int ci = i / 24, r = i - ci * 24;
    x_s[i] = x[(b * CC + ci) * (VV * LL) + v0 * LL + r];
  }
  __syncthreads();

  // wa[h][which][ci] = sum_c W[h][ci][c]*a[h][which][c] (rotated, no conflicts)
  {
    int h = tid >> 6, which = (tid >> 5) & 1, ci = tid & 31;
    float acc = 0.f;
#pragma unroll
    for (int k = 0; k < CC; ++k) {
      int c = (k + ci) & 31;
      acc = fmaf(W_lds[h * CC * CC + ci * CC + c],
                 a_lds[h * 2 * CC + which * CC + c], acc);
    }
    wa[h][which][ci] = acc;
  }
  __syncthreads();

  const int vp = tid >> 7;          // wave-uniform (waves 0,1 -> vp0; 2,3 -> vp1)
  const int h = (tid >> 5) & 3;
  const int c = tid & 31;
  const int v = v0 + vp;

  int xoff = (b * CC) * (VV * LL) + v * LL;
  xoff = __builtin_amdgcn_readfirstlane(xoff);
  const float* xr = x + xoff;

  float acc[LL];
#pragma unroll
  for (int l = 0; l < LL; ++l) acc[l] = 0.f;

#pragma unroll 4
  for (int ci = 0; ci < CC; ++ci) {
    float w = W_lds[h * CC * CC + ci * CC + c];
#pragma unroll
    for (int l = 0; l < LL; ++l)
      acc[l] = fmaf(xr[ci * (VV * LL) + l], w, acc[l]);
  }

  const int slab0 = h * NBL + b * LL;
#pragma unroll
  for (int l = 0; l < LL; ++l) {
    __half hv = __float2half(acc[l]);
    h_g[((size_t)(slab0 + l) * VV + v) * CC + c] = *(ushort*)&hv;
  }

  // s_src/s_dst: 192 threads cover (vp2, h2, l, which)
  if (tid < 192) {
    int which = tid & 1;
    int t2 = tid >> 1;            // 0..95
    int l = t2 % 12;
    int h2 = (t2 / 12) & 3;
    int vp2 = t2 / 48;
    float s = 0.f;
#pragma unroll
    for (int ci = 0; ci < CC; ++ci)
      s = fmaf(x_s[ci * 24 + vp2 * 12 + l], wa[h2][which][ci], s);
    int slab = h2 * NBL + b * LL + l;
    float* dp = which ? s_dst : s_src;
    dp[slab * VV + v0 + vp2] = s;
  }
}

// ---------------------------------------------------------------------------
// k_scatter: padded-CSR build via atomic append; entry = {dst, lv} packed.
// ---------------------------------------------------------------------------
__global__ __launch_bounds__(256) void k_scatter(const int* __restrict__ ei,
                                                 const float* __restrict__ ev,
                                                 int* __restrict__ cnt,
                                                 uint2* __restrict__ csr) {
  int e = blockIdx.x * 256 + threadIdx.x;
  if (e >= EE) return;
  int r = ei[e];
  int d = ei[EE + e];
  int pos = atomicAdd(&cnt[r], 1);
  if (pos < RCAP) {
    float lv = fmaxf(__logf(ev[e]), NEG_CAP_F);
    csr[r * RCAP + pos] = make_uint2((uint)d, __float_as_uint(lv));
  }
}

// ---------------------------------------------------------------------------
// k_agg: one wave per (v, bl).
// Phase A (16-edge chunk): lanes = 16 edges x 4 h -> one exp per (edge,h);
//   all 16 slots rewritten every chunk (slots >= m hold ee=0, dst=0), phases
//   are sequential within the wave -> no double buffer, no barrier.
// Phase B: lane = ii(4 edge-slots) x h(4) x cg(4); per iter: 2 broadcast DS
//   reads + v_lshl_add_u32 voffset + ONE dwordx4 gather (8 f16 channels of
//   lane's h) + 8 v_fma_mix_f32 (f16 operand straight from register halves).
// Tail: xor-16/32 (edge-slots) then xor-4/8 (heads); fused mean+ELU; 16
// lanes write 2 dwords each. XCD swizzle: same-bl stretches per XCD slot.
// ---------------------------------------------------------------------------
__global__ __launch_bounds__(256) void k_agg(const ushort* __restrict__ hg,
                                             const float* __restrict__ s_src,
                                             const float* __restrict__ s_dst,
                                             const int* __restrict__ cnt,
                                             const uint2* __restrict__ csr,
                                             float* __restrict__ outp) {
  __shared__ uint ed_dst[4][16];        // [warp][edge]
  __shared__ float ed_ee[4][16][HH];    // [warp][edge][h]
  const int i = blockIdx.x;
  const int xcd = i & 7;
  const int q = i >> 3;                // 0..1499
  const int bl = xcd * 6 + q / 250;    // 0..47
  const int vb = q % 250;
  const int warp = threadIdx.x >> 6;
  const int v = vb * 4 + warp;
  const int lane = threadIdx.x & 63;
  const int b = bl / LL, l = bl - b * LL;

  int deg = cnt[v];
  if (deg > RCAP) deg = RCAP;
  const int rbase = v * RCAP;

  // phase-A role: lane = ha*16 + ia
  const int ha = lane >> 4;
  const int ia = lane & 15;
  const int slabA = ha * NBL + bl;
  const float ssv = s_src[slabA * VV + v];
  const float* sdbA = s_dst + slabA * VV;

  // phase-B role: lane = ii*16 + h*4 + cg
  const int ii = lane >> 4;
  const int h = (lane >> 2) & 3;
  const int cg = lane & 3;

  // per-lane byte offset of (slab, channel-group) within hg; dst adds d*64
  const uint hoff = (uint)((h * NBL + bl) * (VV * CC * 2)) + (uint)(cg * 16);
  const char* hgbytes = (const char*)hg;

  float num[8];
#pragma unroll
  for (int j = 0; j < 8; ++j) num[j] = 0.f;
  float rs = 0.f;

  for (int base = 0; base < deg; base += 16) {
    // ---- phase A ----
    int e = base + ia;
    float eev = 0.f;
    int d = 0;
    if (e < deg) {
      uint2 ent = csr[rbase + e];
      d = (int)ent.x;
      float lv = __uint_as_float(ent.y);
      float s = ssv + sdbA[d];
      float lr = s > 0.f ? s : LALPHA * s;
      eev = __expf(-lr) * lv;
    }
    ed_ee[warp][ia][ha] = eev;
    if (ha == 0) ed_dst[warp][ia] = (uint)d;

    // ---- phase B: 4 edges x (4h x 32c) per iter ----
    int m = deg - base;
    if (m > 16) m = 16;
    int iters = (m + 3) >> 2;
    for (int t = 0; t < iters; ++t) {
      int idx = (t << 2) + ii;     // <= 15 always
      uint d2 = ed_dst[warp][idx];
      float eh = ed_ee[warp][idx][h];
      uint voff = (d2 << 6) + hoff;
      uint4 g = *(const uint4*)(hgbytes + voff);   // 8 f16 channels
      __half2 p0 = __builtin_bit_cast(__half2, g.x);
      __half2 p1 = __builtin_bit_cast(__half2, g.y);
      __half2 p2 = __builtin_bit_cast(__half2, g.z);
      __half2 p3 = __builtin_bit_cast(__half2, g.w);
      num[0] = fmaf(eh, __low2float(p0), num[0]);
      num[1] = fmaf(eh, __high2float(p0), num[1]);
      num[2] = fmaf(eh, __low2float(p1), num[2]);
      num[3] = fmaf(eh, __high2float(p1), num[3]);
      num[4] = fmaf(eh, __low2float(p2), num[4]);
      num[5] = fmaf(eh, __high2float(p2), num[5]);
      num[6] = fmaf(eh, __low2float(p3), num[6]);
      num[7] = fmaf(eh, __high2float(p3), num[7]);
      rs += eh;
    }
  }

  // reduce over edge-slots (ii): xor 16, 32
#pragma unroll
  for (int mm = 16; mm <= 32; mm <<= 1) {
#pragma unroll
    for (int j = 0; j < 8; ++j) num[j] += __shfl_xor(num[j], mm);
    rs += __shfl_xor(rs, mm);
  }
  float inv = __frcp_rn(rs);
  float val[8];
#pragma unroll
  for (int j = 0; j < 8; ++j) val[j] = num[j] * inv;
  // reduce over heads (h bits): xor 4, 8
#pragma unroll
  for (int mm = 4; mm <= 8; mm <<= 1) {
#pragma unroll
    for (int j = 0; j < 8; ++j) val[j] += __shfl_xor(val[j], mm);
  }

  if (ii == 0) {
    int j0 = 2 * h;               // lane (h,cg) writes channels cg*8+2h, +1
    float a0 = val[j0] * 0.25f;
    float a1 = val[j0 + 1] * 0.25f;
    a0 = a0 > 0.f ? a0 : expm1f(a0);
    a1 = a1 > 0.f ? a1 : expm1f(a1);
    size_t o0 = ((size_t)(b * CC + cg * 8 + j0) * VV + v) * LL + l;
    outp[o0] = a0;
    outp[o0 + (size_t)VV * LL] = a1;
  }
}

// ---------------------------------------------------------------------------
extern "C" void kernel_launch(void* const* d_in, const int* in_sizes, int n_in,
                              void* d_out, int out_size, void* d_ws, size_t ws_size,
                              hipStream_t stream) {
  const float* x = (const float*)d_in[0];
  const float* W = (const float*)d_in[1];
  const float* a = (const float*)d_in[2];
  const int* ei = (const int*)d_in[3];
  const float* ev = (const float*)d_in[4];
  float* out = (float*)d_out;
  float* ws = (float*)d_ws;

  size_t o = 0;
  ushort* h_g = (ushort*)(ws + o);  o += (size_t)SS * VV * CC / 2;   // f16, 12.3 MB
  float* s_src = ws + o;            o += SS * VV;
  float* s_dst = ws + o;            o += SS * VV;
  int* cnt = (int*)(ws + o);        o += 1024;
  uint2* csr = (uint2*)(ws + o);    o += (size_t)VV * RCAP * 2;      // {dst, lv}

  dim3 gA(VV / 2, BB);
  k_h<<<gA, 256, 0, stream>>>(x, W, a, h_g, s_src, s_dst, cnt);

  k_scatter<<<(EE + 255) / 256, 256, 0, stream>>>(ei, ev, cnt, csr);

  const int nblk = NBL * (VV / 4);  // 12000 blocks, 4 waves each
  k_agg<<<nblk, 256, 0, stream>>>(h_g, s_src, s_dst, cnt, csr, out);
}